// Round 1
// 1062.440 us; speedup vs baseline: 1.0285x; 1.0285x over previous
//
#include <hip/hip_runtime.h>

// n=2048 rows, f=32 features. Output row r = [emb[i] (32) | emb[j] (32) | sw[j]],
// i = r>>11, j = r&2047. Output 2048*2048*65 f32 = 1.09 GB -> write-BW bound.
//
// v2: persistent-ish blocks + double-buffered LDS + register-staged fill.
//  - 4096 blocks x 256 threads; block b owns 16 CONSECUTIVE 64-row tiles
//    (contiguous 266 KB output span per block).
//  - i = tile/32 is CONSTANT per block (16 | 32): the emb[i] half of every
//    LDS row is written ONCE into both buffers at block start.
//  - Per tile, the emb[j] source is a contiguous 8 KB span (rows j0..j0+63):
//    2 x global_load_dwordx4 per thread, staged in registers.
//  - Pipeline per tile: load regs(tile k+1) -> drain buf[cur] (ds_read_b128 +
//    global_store_dwordx4) -> ds_write regs into buf[cur^1] -> barrier.
//    One barrier per tile; next tile's L2 latency hides under current drain.

#define NROWS 2048
#define TILE_ROWS 64
#define ROWF 65
#define TILE_FLOATS (TILE_ROWS * ROWF)            // 4160
#define TILE_F4 (TILE_FLOATS / 4)                 // 1040
#define TILES_TOTAL ((NROWS * NROWS) / TILE_ROWS) // 65536
#define TILES_PER_BLOCK 16
#define NBLOCKS (TILES_TOTAL / TILES_PER_BLOCK)   // 4096

__global__ __launch_bounds__(256) void expand_dbuf(
    const float* __restrict__ emb,   // [2048*32]
    const float* __restrict__ sw,    // [2048]
    float4* __restrict__ out)        // flat output as float4
{
    __shared__ __align__(16) float lds[2][TILE_FLOATS];   // 33,280 B

    const unsigned tid = threadIdx.x;
    const unsigned t0  = blockIdx.x * TILES_PER_BLOCK;
    const unsigned i   = t0 / 32u;                 // constant per block

    // ---- I-part: written once into BOTH buffers, never touched again ----
    // thread covers row rr = tid>>2, cols c0..c0+7 where c0 = 8*(tid&3)
    {
        const unsigned rr = tid >> 2;
        const unsigned c0 = (tid & 3u) * 8u;
        const float4 viA = *(const float4*)(emb + i * 32u + c0);
        const float4 viB = *(const float4*)(emb + i * 32u + c0 + 4u);
#pragma unroll
        for (unsigned b = 0; b < 2; ++b) {
            float* d = &lds[b][rr * ROWF + c0];
            d[0] = viA.x; d[1] = viA.y; d[2] = viA.z; d[3] = viA.w;
            d[4] = viB.x; d[5] = viB.y; d[6] = viB.z; d[7] = viB.w;
        }
    }

    // ---- J-part register staging mapping (fixed per thread) ----
    // f4 #q of the 512-f4 contiguous J-span -> row jr=q>>3, col 32+4*(q&7).
    const unsigned jr0 = tid >> 3;          // q0 = tid      -> rows 0..31
    const unsigned jr1 = jr0 + 32u;         // q1 = tid+256  -> rows 32..63
    const unsigned cs  = (tid & 7u) * 4u;

    float4 ja, jb;
    float  s = 0.0f;

    auto load_tile = [&](unsigned tile) {
        const unsigned j0  = (tile & 31u) * 64u;          // never wraps
        const float4*  src = (const float4*)(emb + j0 * 32u);
        ja = src[tid];
        jb = src[tid + 256u];
        if (tid < 64u) s = sw[j0 + tid];
    };
    auto write_js = [&](unsigned b) {
        float* d0 = &lds[b][jr0 * ROWF + 32u + cs];
        d0[0] = ja.x; d0[1] = ja.y; d0[2] = ja.z; d0[3] = ja.w;
        float* d1 = &lds[b][jr1 * ROWF + 32u + cs];
        d1[0] = jb.x; d1[1] = jb.y; d1[2] = jb.z; d1[3] = jb.w;
        if (tid < 64u) lds[b][tid * ROWF + 64u] = s;
    };

    // ---- prologue: stage tile 0 into buf 0 ----
    load_tile(t0);
    write_js(0);
    __syncthreads();

    unsigned cur = 0;
#pragma unroll 1
    for (unsigned kk = 0; kk < TILES_PER_BLOCK; ++kk) {
        const unsigned tile = t0 + kk;

        // issue next tile's global loads early (latency hides under drain)
        if (kk + 1u < TILES_PER_BLOCK) load_tile(tile + 1u);

        // drain buf[cur]: 1040 f4, unit-stride b128 reads + dwordx4 stores
        {
            const float4* b4   = (const float4*)lds[cur];
            const unsigned base = tile * TILE_F4;   // < 2^27, 32-bit safe
#pragma unroll
            for (unsigned p = 0; p < 5; ++p) {
                const unsigned idx = p * 256u + tid;
                if (idx < TILE_F4) out[base + idx] = b4[idx];
            }
        }

        // fill the other buffer from staged registers
        if (kk + 1u < TILES_PER_BLOCK) write_js(cur ^ 1u);

        __syncthreads();
        cur ^= 1u;
    }
}

extern "C" void kernel_launch(void* const* d_in, const int* in_sizes, int n_in,
                              void* d_out, int out_size, void* d_ws, size_t ws_size,
                              hipStream_t stream) {
    const float* emb = (const float*)d_in[0];   // [2048, 32] f32
    const float* sw  = (const float*)d_in[1];   // [2048] f32
    float4* out      = (float4*)d_out;

    expand_dbuf<<<dim3(NBLOCKS), dim3(256), 0, stream>>>(emb, sw, out);
}